// Round 1
// baseline (776.860 us; speedup 1.0000x reference)
//
#include <hip/hip_runtime.h>
#include <hip/hip_bf16.h>
#include <stdint.h>
#include <stddef.h>

// Problem constants (fixed by the reference)
#define N_TOT  8192   // rows of adj / rows of x
#define D_FEAT 256    // feature dim
// Tile config
#define BM 64
#define BN 256
#define BK 64
#define LDK 72        // padded LDS row stride (bf16 elems): 144 B = 36 dwords -> even bank spread
#define K_ITERS (N_TOT / BK)   // 128

typedef float f32x4_t __attribute__((ext_vector_type(4)));
typedef short s16x8_t __attribute__((ext_vector_type(8)));

// fp32 -> bf16 round-to-nearest-even (inputs are finite; no NaN handling needed)
__device__ __forceinline__ unsigned short f2bf(float f) {
    union { float f; unsigned int u; } a;
    a.f = f;
    unsigned int r = a.u + 0x7FFFu + ((a.u >> 16) & 1u);
    return (unsigned short)(r >> 16);
}

__device__ __forceinline__ unsigned int pack2(float lo, float hi) {
    return (unsigned int)f2bf(lo) | ((unsigned int)f2bf(hi) << 16);
}

// out[m, g*256 + n] = sum_k adj_g[m,k] * x[k,n]
__global__ __launch_bounds__(256, 1) void h2gcn_kernel(
    const float* __restrict__ x,
    const float* __restrict__ adj0,
    const float* __restrict__ adj1,
    float* __restrict__ out)
{
    const int g  = blockIdx.y;
    const float* __restrict__ adj = g ? adj1 : adj0;
    const int m0 = blockIdx.x * BM;
    const int t  = threadIdx.x;
    const int lane = t & 63;
    const int wv   = t >> 6;       // wave id 0..3 -> owns cols [64*wv, 64*wv+64)
    const int fl = lane & 15;      // fragment row/col index
    const int fq = lane >> 4;      // fragment quad

    __shared__ __align__(16) unsigned short Asm[BM * LDK];  //  9.0 KiB (bf16 A tile)
    __shared__ __align__(16) unsigned short Bsm[BN * LDK];  // 36.0 KiB (bf16 x tile, transposed: [n][k])

    // ---- A staging assignment: thread -> (row a_row+16i, k-chunk of 4) ----
    const int a_row = t >> 4;          // 0..15 (then +16*i)
    const int a_c4  = (t & 15) * 4;    // k offset (float4)
    // ---- B staging assignment: thread -> cols {2np, 2np+1}, k in [32kh, 32kh+32) ----
    const int np = t & 127;
    const int kh = t >> 7;

    const float* aBase = adj + (size_t)m0 * N_TOT;

    float4 a_reg[4];
    float2 b_reg[32];

    // prologue: load tile 0 into registers
    {
        #pragma unroll
        for (int i = 0; i < 4; ++i)
            a_reg[i] = *(const float4*)(aBase + (size_t)(a_row + 16 * i) * N_TOT + a_c4);
        #pragma unroll
        for (int j = 0; j < 32; ++j)
            b_reg[j] = *(const float2*)(x + (size_t)(32 * kh + j) * D_FEAT + 2 * np);
    }

    f32x4_t acc[4][4];
    #pragma unroll
    for (int i = 0; i < 4; ++i)
        #pragma unroll
        for (int j = 0; j < 4; ++j) {
            f32x4_t z = {0.0f, 0.0f, 0.0f, 0.0f};
            acc[i][j] = z;
        }

    for (int it = 0; it < K_ITERS; ++it) {
        __syncthreads();   // all waves done reading LDS of previous tile

        // ---- convert + store registers -> LDS (bf16) ----
        #pragma unroll
        for (int i = 0; i < 4; ++i) {
            ushort4 v;
            v.x = f2bf(a_reg[i].x); v.y = f2bf(a_reg[i].y);
            v.z = f2bf(a_reg[i].z); v.w = f2bf(a_reg[i].w);
            *(ushort4*)&Asm[(a_row + 16 * i) * LDK + a_c4] = v;   // 8B write
        }
        #pragma unroll
        for (int s = 0; s < 2; ++s) {      // which of the thread's two columns
            #pragma unroll
            for (int u = 0; u < 4; ++u) {  // 8-k chunk within our 32-k span
                uint4 w;
                if (s == 0) {
                    w.x = pack2(b_reg[8*u+0].x, b_reg[8*u+1].x);
                    w.y = pack2(b_reg[8*u+2].x, b_reg[8*u+3].x);
                    w.z = pack2(b_reg[8*u+4].x, b_reg[8*u+5].x);
                    w.w = pack2(b_reg[8*u+6].x, b_reg[8*u+7].x);
                } else {
                    w.x = pack2(b_reg[8*u+0].y, b_reg[8*u+1].y);
                    w.y = pack2(b_reg[8*u+2].y, b_reg[8*u+3].y);
                    w.z = pack2(b_reg[8*u+4].y, b_reg[8*u+5].y);
                    w.w = pack2(b_reg[8*u+6].y, b_reg[8*u+7].y);
                }
                // B stored transposed: row n = 2np+s, k offset 32kh + 8u (16B aligned)
                *(uint4*)&Bsm[(2 * np + s) * LDK + 32 * kh + 8 * u] = w;
            }
        }

        __syncthreads();   // LDS tile ready

        // ---- issue next tile's global loads (overlap with MFMA below) ----
        if (it + 1 < K_ITERS) {
            const size_t k0 = (size_t)(it + 1) * BK;
            #pragma unroll
            for (int i = 0; i < 4; ++i)
                a_reg[i] = *(const float4*)(aBase + (size_t)(a_row + 16 * i) * N_TOT + k0 + a_c4);
            #pragma unroll
            for (int j = 0; j < 32; ++j)
                b_reg[j] = *(const float2*)(x + (k0 + (size_t)(32 * kh + j)) * D_FEAT + 2 * np);
        }

        // ---- MFMA on current tile ----
        #pragma unroll
        for (int ks = 0; ks < 2; ++ks) {
            s16x8_t af[4], bf[4];
            #pragma unroll
            for (int mt = 0; mt < 4; ++mt)
                af[mt] = *(const s16x8_t*)&Asm[(16 * mt + fl) * LDK + 32 * ks + 8 * fq];
            #pragma unroll
            for (int nt = 0; nt < 4; ++nt)
                bf[nt] = *(const s16x8_t*)&Bsm[(wv * 64 + 16 * nt + fl) * LDK + 32 * ks + 8 * fq];
            #pragma unroll
            for (int mt = 0; mt < 4; ++mt)
                #pragma unroll
                for (int nt = 0; nt < 4; ++nt)
                    acc[mt][nt] = __builtin_amdgcn_mfma_f32_16x16x32_bf16(
                        af[mt], bf[nt], acc[mt][nt], 0, 0, 0);
        }
    }

    // ---- epilogue: C/D layout col=lane&15, row=(lane>>4)*4+reg ----
    #pragma unroll
    for (int mt = 0; mt < 4; ++mt)
        #pragma unroll
        for (int nt = 0; nt < 4; ++nt)
            #pragma unroll
            for (int r = 0; r < 4; ++r) {
                const int row = m0 + 16 * mt + fq * 4 + r;
                const int col = g * D_FEAT + wv * 64 + 16 * nt + fl;
                out[(size_t)row * (2 * D_FEAT) + col] = acc[mt][nt][r];
            }
}

extern "C" void kernel_launch(void* const* d_in, const int* in_sizes, int n_in,
                              void* d_out, int out_size, void* d_ws, size_t ws_size,
                              hipStream_t stream) {
    const float* x      = (const float*)d_in[0];
    const float* adj_t  = (const float*)d_in[1];
    const float* adj_t2 = (const float*)d_in[2];
    float* out = (float*)d_out;
    (void)in_sizes; (void)n_in; (void)out_size; (void)d_ws; (void)ws_size;

    dim3 grid(N_TOT / BM, 2);   // 128 row-tiles x 2 adjacency matrices = 256 blocks (1/CU)
    dim3 block(256);
    hipLaunchKernelGGL(h2gcn_kernel, grid, block, 0, stream, x, adj_t, adj_t2, out);
}

// Round 2
// 680.699 us; speedup vs baseline: 1.1413x; 1.1413x over previous
//
#include <hip/hip_runtime.h>
#include <stdint.h>
#include <stddef.h>

// Problem constants (fixed by the reference)
#define N_TOT  8192   // rows of adj / rows of x
#define D_FEAT 256    // feature dim
// Main-kernel tile config
#define BM 32         // rows per block
#define BK 64         // k per iteration
#define LDK 72        // padded LDS row stride (bf16 elems); 144 B = 16B-aligned rows
#define K_ITERS (N_TOT / BK)   // 128

typedef float f32x4_t __attribute__((ext_vector_type(4)));
typedef short s16x8_t __attribute__((ext_vector_type(8)));

// fp32 -> bf16 round-to-nearest-even (inputs finite)
__device__ __forceinline__ unsigned short f2bf(float f) {
    union { float f; unsigned int u; } a;
    a.f = f;
    unsigned int r = a.u + 0x7FFFu + ((a.u >> 16) & 1u);
    return (unsigned short)(r >> 16);
}

// ---------------------------------------------------------------------------
// Pre-kernel: xT[n][k] = bf16(x[k][n]).  x: [8192][256] fp32 -> xT: [256][8192] bf16
// ---------------------------------------------------------------------------
__global__ __launch_bounds__(256) void xpose_kernel(
    const float* __restrict__ x, unsigned short* __restrict__ xT)
{
    __shared__ unsigned short T[64 * 72];   // [n][k] tile, stride 72 -> 16B-aligned rows
    const int t  = threadIdx.x;
    const int k0 = blockIdx.x * 64;
    const int n0 = blockIdx.y * 64;

    #pragma unroll
    for (int i = 0; i < 4; ++i) {
        const int kr = (t >> 4) + 16 * i;
        const int c4 = (t & 15) * 4;
        float4 v = *(const float4*)(x + (size_t)(k0 + kr) * D_FEAT + n0 + c4);
        T[(c4 + 0) * 72 + kr] = f2bf(v.x);
        T[(c4 + 1) * 72 + kr] = f2bf(v.y);
        T[(c4 + 2) * 72 + kr] = f2bf(v.z);
        T[(c4 + 3) * 72 + kr] = f2bf(v.w);
    }
    __syncthreads();
    #pragma unroll
    for (int i = 0; i < 2; ++i) {
        const int n  = (t >> 3) + 32 * i;
        const int c8 = (t & 7) * 8;
        uint4 w = *(const uint4*)&T[n * 72 + c8];
        *(uint4*)(xT + (size_t)(n0 + n) * N_TOT + k0 + c8) = w;
    }
}

// ---------------------------------------------------------------------------
// Main kernel: out[m, g*256 + n] = sum_k adj_g[m,k] * x[k,n]
// Block: 512 thr = 8 waves; wave w owns cols [32w, 32w+32).  BM=32 rows.
// A (fp32, HBM) staged via 4.4 KiB LDS (bf16 convert); B read directly from
// L2-resident bf16 xT in MFMA fragment layout. 1-deep register prefetch.
// ---------------------------------------------------------------------------
__global__ __launch_bounds__(512, 4) void h2gcn_kernel(
    const float* __restrict__ adj0,
    const float* __restrict__ adj1,
    const unsigned short* __restrict__ xT,
    float* __restrict__ out)
{
    const int g  = blockIdx.y;
    const float* __restrict__ adj = g ? adj1 : adj0;
    const int m0   = blockIdx.x * BM;
    const int t    = threadIdx.x;
    const int lane = t & 63;
    const int w    = t >> 6;      // wave 0..7
    const int fl   = lane & 15;   // fragment row/col
    const int fq   = lane >> 4;   // fragment quad

    __shared__ __align__(16) unsigned short Asm[BM * LDK];  // 4608 B

    // A staging: thread -> (row, 4-wide k chunk); one float4 per thread
    const int a_row = t >> 4;          // 0..31
    const int a_c4  = (t & 15) * 4;    // 0..60

    const float* aBase = adj + (size_t)m0 * N_TOT + (size_t)a_row * N_TOT + a_c4;

    // B fragment addresses: row n = 32w + 16nt + fl of xT
    const unsigned short* bBase0 = xT + (size_t)(32 * w + fl) * N_TOT + 8 * fq;
    const unsigned short* bBase1 = bBase0 + (size_t)16 * N_TOT;

    float4 a_reg = *(const float4*)aBase;

    s16x8_t b[2][2][2];   // [buf][nt][ks]
    #pragma unroll
    for (int ks = 0; ks < 2; ++ks) {
        b[0][0][ks] = *(const s16x8_t*)(bBase0 + 32 * ks);
        b[0][1][ks] = *(const s16x8_t*)(bBase1 + 32 * ks);
    }

    f32x4_t acc[2][2];
    #pragma unroll
    for (int mt = 0; mt < 2; ++mt)
        #pragma unroll
        for (int nt = 0; nt < 2; ++nt) {
            f32x4_t z = {0.0f, 0.0f, 0.0f, 0.0f};
            acc[mt][nt] = z;
        }

    #pragma unroll 2
    for (int it = 0; it < K_ITERS; ++it) {
        const int cur = it & 1;
        const int nxt = cur ^ 1;

        __syncthreads();   // previous tile's LDS reads complete
        {
            ushort4 v;
            v.x = f2bf(a_reg.x); v.y = f2bf(a_reg.y);
            v.z = f2bf(a_reg.z); v.w = f2bf(a_reg.w);
            *(ushort4*)&Asm[a_row * LDK + a_c4] = v;
        }
        __syncthreads();   // A tile ready

        // prefetch next iteration (overlaps MFMA below)
        if (it + 1 < K_ITERS) {
            const size_t k0 = (size_t)(it + 1) * BK;
            a_reg = *(const float4*)(aBase + k0);
            #pragma unroll
            for (int ks = 0; ks < 2; ++ks) {
                b[nxt][0][ks] = *(const s16x8_t*)(bBase0 + k0 + 32 * ks);
                b[nxt][1][ks] = *(const s16x8_t*)(bBase1 + k0 + 32 * ks);
            }
        }

        // A fragments from LDS
        s16x8_t af[2][2];
        #pragma unroll
        for (int mt = 0; mt < 2; ++mt)
            #pragma unroll
            for (int ks = 0; ks < 2; ++ks)
                af[mt][ks] = *(const s16x8_t*)&Asm[(16 * mt + fl) * LDK + 32 * ks + 8 * fq];

        #pragma unroll
        for (int ks = 0; ks < 2; ++ks)
            #pragma unroll
            for (int mt = 0; mt < 2; ++mt)
                #pragma unroll
                for (int nt = 0; nt < 2; ++nt)
                    acc[mt][nt] = __builtin_amdgcn_mfma_f32_16x16x32_bf16(
                        af[mt][ks], b[cur][nt][ks], acc[mt][nt], 0, 0, 0);
    }

    // epilogue: C/D layout col=lane&15, row=(lane>>4)*4+reg
    #pragma unroll
    for (int mt = 0; mt < 2; ++mt)
        #pragma unroll
        for (int nt = 0; nt < 2; ++nt)
            #pragma unroll
            for (int r = 0; r < 4; ++r) {
                const int row = m0 + 16 * mt + 4 * fq + r;
                const int col = g * D_FEAT + 32 * w + 16 * nt + fl;
                out[(size_t)row * (2 * D_FEAT) + col] = acc[mt][nt][r];
            }
}

extern "C" void kernel_launch(void* const* d_in, const int* in_sizes, int n_in,
                              void* d_out, int out_size, void* d_ws, size_t ws_size,
                              hipStream_t stream) {
    const float* x      = (const float*)d_in[0];
    const float* adj_t  = (const float*)d_in[1];
    const float* adj_t2 = (const float*)d_in[2];
    float* out = (float*)d_out;
    unsigned short* xT = (unsigned short*)d_ws;   // 256*8192 bf16 = 4 MiB
    (void)in_sizes; (void)n_in; (void)out_size; (void)ws_size;

    // 1) transpose+convert x -> xT (bf16, [n][k])
    hipLaunchKernelGGL(xpose_kernel, dim3(N_TOT / 64, D_FEAT / 64), dim3(256), 0, stream, x, xT);
    // 2) fused dual GEMM. 256 m-tiles x 2 matrices = 512 blocks (2/CU, 16 waves/CU)
    hipLaunchKernelGGL(h2gcn_kernel, dim3(N_TOT / BM, 2), dim3(512), 0, stream,
                       adj_t, adj_t2, xT, out);
}